// Round 12
// baseline (1213.989 us; speedup 1.0000x reference)
//
#include <hip/hip_runtime.h>
#include <math.h>

// Problem constants
#define BG 1024
#define EPG 512
#define ETOT (BG*EPG)
#define DIM 512
#define KP1 52
#define KP2 42
#define KP3 34
#define OFS 80   // stride of per-graph offset tables

typedef unsigned int uint;
typedef short s16x8 __attribute__((ext_vector_type(8)));
typedef float f32x4 __attribute__((ext_vector_type(4)));

// ---------------- bf16 split helpers ----------------
__device__ __forceinline__ unsigned short f2b(float x) {
    uint u = __float_as_uint(x);
    u = u + 0x7fffu + ((u >> 16) & 1u);
    return (unsigned short)(u >> 16);
}
__device__ __forceinline__ float b2f(unsigned short h) {
    return __uint_as_float(((uint)h) << 16);
}
__device__ __forceinline__ void splitf(float x, unsigned short& h, unsigned short& l) {
    h = f2b(x);
    l = f2b(x - b2f(h));
}
__device__ __forceinline__ uint pk2(unsigned short a, unsigned short b) {
    return (uint)a | ((uint)b << 16);
}

__device__ __forceinline__ void gload16(const void* g, void* l) {
    __builtin_amdgcn_global_load_lds(
        (const __attribute__((address_space(1))) void*)g,
        (__attribute__((address_space(3))) void*)l, 16, 0, 0);
}

// ---------------------------------------------------------------------------
// 1. Weight convert, all 6 weights in one launch
// ---------------------------------------------------------------------------
struct WPtrs { const float* w[6]; };

__global__ void __launch_bounds__(256)
split_wT_all(WPtrs p, unsigned short* __restrict__ WT)
{
    const int wi = blockIdx.x >> 8;
    const int bb = blockIdx.x & 255;
    const float* W = p.w[wi];
    unsigned short* Thi = WT + (size_t)(2 * wi) * DIM * DIM;
    unsigned short* Tlo = Thi + (size_t)DIM * DIM;
    __shared__ float tl[32][33];
    const int t  = threadIdx.x;
    const int bx = bb & 15;
    const int by = bb >> 4;
    const int lx = t & 31, ly = t >> 5;
    for (int r = ly; r < 32; r += 8)
        tl[r][lx] = W[(size_t)(by*32 + r) * DIM + bx*32 + lx];
    __syncthreads();
    for (int r = ly; r < 32; r += 8) {
        float v = tl[lx][r];
        unsigned short h, l; splitf(v, h, l);
        size_t o = (size_t)(bx*32 + r) * DIM + by*32 + lx;
        Thi[o] = h; Tlo[o] = l;
    }
}

// ---------------------------------------------------------------------------
// 2. Layer-1 edge sort: counting sort by local dst, packed (dst<<16|src)
// ---------------------------------------------------------------------------
__global__ void __launch_bounds__(256)
sort_edges1(const int* __restrict__ esrc, const int* __restrict__ edst,
            uint* __restrict__ SE, int* __restrict__ OF)
{
    const int g = blockIdx.x;
    const int t = threadIdx.x;
    __shared__ int ld[EPG];
    __shared__ int ls[EPG];
    __shared__ int cnt4[4][64];
    __shared__ int offs[65];
    const int eb = g * EPG;
    for (int e = t; e < EPG; e += 256) {
        ld[e] = edst[eb + e] - g * 64;
        ls[e] = esrc[eb + e] - g * 64;
    }
    __syncthreads();
    {
        const int d = t & 63, q = t >> 6;
        int c = 0;
        for (int e = q * 128; e < q * 128 + 128; ++e) c += (ld[e] == d);
        cnt4[q][d] = c;
    }
    __syncthreads();
    if (t == 0) {
        int s = 0;
        for (int i = 0; i < 64; ++i) {
            offs[i] = s;
            s += cnt4[0][i] + cnt4[1][i] + cnt4[2][i] + cnt4[3][i];
        }
        offs[64] = s;
    }
    __syncthreads();
    {
        const int d = t & 63, q = t >> 6;
        int w = offs[d];
        for (int q2 = 0; q2 < q; ++q2) w += cnt4[q2][d];
        for (int e = q * 128; e < q * 128 + 128; ++e)
            if (ld[e] == d) SE[(size_t)g * EPG + (w++)] = ((uint)d << 16) | (uint)ls[e];
    }
    if (t <= 64) OF[g * OFS + t] = offs[t];
}

// ---------------------------------------------------------------------------
// 3. Fused gather + split + layer-1 aggregation, column-sliced.
// ---------------------------------------------------------------------------
__global__ void __launch_bounds__(256, 4)
gather_agg(const int* __restrict__ ids, const float* __restrict__ emb,
           const uint* __restrict__ SE, const int* __restrict__ OF,
           unsigned short* __restrict__ Xhi, unsigned short* __restrict__ Xlo,
           unsigned short* __restrict__ Ghi, unsigned short* __restrict__ Glo)
{
    const int g  = blockIdx.x >> 2;
    const int c0 = (blockIdx.x & 3) * 128;
    const int t  = threadIdx.x;
    __shared__ __align__(16) float xf[64 * 128];   // 32 KB
    __shared__ int lid[64];
    __shared__ uint el[EPG];
    __shared__ int offs[65];

    if (t < 64) lid[t] = ids[g * 64 + t];
    if (t >= 128 && t < 128 + 65) offs[t - 128] = OF[g * OFS + (t - 128)];
    __syncthreads();

    for (int s = t; s < 64 * 32; s += 256) {
        const int row = s >> 5;
        const int c4  = (s & 31) * 4;
        ((float4*)xf)[s] =
            *(const float4*)(emb + (size_t)lid[row] * DIM + c0 + c4);
    }
    const int cnt = offs[64];
    for (int e = t; e < cnt; e += 256) el[e] = SE[(size_t)g * EPG + e];
    __syncthreads();

    for (int s = t; s < 64 * 16; s += 256) {
        const int row = s >> 4;
        const int c8  = (s & 15) * 8;
        const float* src = &xf[row * 128 + c8];
        unsigned short h[8], l[8];
#pragma unroll
        for (int i = 0; i < 8; ++i) splitf(src[i], h[i], l[i]);
        uint4 Hq, Lq;
        Hq.x = pk2(h[0],h[1]); Hq.y = pk2(h[2],h[3]);
        Hq.z = pk2(h[4],h[5]); Hq.w = pk2(h[6],h[7]);
        Lq.x = pk2(l[0],l[1]); Lq.y = pk2(l[2],l[3]);
        Lq.z = pk2(l[4],l[5]); Lq.w = pk2(l[6],l[7]);
        const size_t wo = (size_t)(g * 64 + row) * DIM + c0 + c8;
        *(uint4*)(Xhi + wo) = Hq;
        *(uint4*)(Xlo + wo) = Lq;
    }

    const int ch = (t & 31) * 4;
    const int d0 = t >> 5;
    for (int d = d0; d < 64; d += 8) {
        const int cA = offs[d], cB = offs[d + 1];
        float s0 = 0.f, s1 = 0.f, s2 = 0.f, s3 = 0.f;
        for (int j = cA; j < cB; ++j) {
            const float* r = &xf[(int)(el[j] & 0xffffu) * 128 + ch];
            s0 += r[0]; s1 += r[1]; s2 += r[2]; s3 += r[3];
        }
        const float den = fmaxf((float)(cB - cA), 1.0f);
        s0 /= den; s1 /= den; s2 /= den; s3 /= den;
        unsigned short h0,h1,h2,h3,l0,l1,l2,l3;
        splitf(s0,h0,l0); splitf(s1,h1,l1); splitf(s2,h2,l2); splitf(s3,h3,l3);
        const size_t wo = (size_t)(g * 64 + d) * DIM + c0 + ch;
        *(uint2*)(Ghi + wo) = make_uint2(pk2(h0,h1), pk2(h2,h3));
        *(uint2*)(Glo + wo) = make_uint2(pk2(l0,l1), pk2(l2,l3));
    }
}

// ---------------------------------------------------------------------------
// 4. Split-bf16 MFMA GEMM (round-8 version: proven local optimum)
//    + fused per-row score partials (y . p per N-block)
// ---------------------------------------------------------------------------
__global__ void __launch_bounds__(256)
gemm_sage(const unsigned short* __restrict__ Ghi, const unsigned short* __restrict__ Glo,
          const unsigned short* __restrict__ WLhi, const unsigned short* __restrict__ WLlo,
          const unsigned short* __restrict__ Xhi, const unsigned short* __restrict__ Xlo,
          const unsigned short* __restrict__ WRhi, const unsigned short* __restrict__ WRlo,
          const float* __restrict__ bias, const float* __restrict__ pvec,
          float* __restrict__ C, float* __restrict__ SC4, int M)
{
    __shared__ unsigned short sA[128 * 64];
    __shared__ unsigned short sW[128 * 64];
    __shared__ float scp[128][2];

    const int t = threadIdx.x;
    const uint nwg = gridDim.x;
    const uint q8  = nwg >> 3;
    const uint bid = blockIdx.x;
    const uint sw  = (bid & 7) * q8 + (bid >> 3);
    const int  m0  = (int)(sw >> 2) * 128;
    const int  n0  = (int)(sw & 3) * 128;

    const int l  = t & 63;
    const int w  = t >> 6;
    const int wr = w >> 1;
    const int wc = w & 1;
    const int lr = l & 15;
    const int lq = l >> 4;

    f32x4 acc[4][4];
#pragma unroll
    for (int i = 0; i < 4; ++i)
#pragma unroll
        for (int j = 0; j < 4; ++j) acc[i][j] = (f32x4){0.f, 0.f, 0.f, 0.f};

    uint srow[4], soff[4];
#pragma unroll
    for (int i = 0; i < 4; ++i) {
        uint p = (uint)i * 256u + (uint)t;
        uint row = p >> 3, pc = p & 7;
        srow[i] = row;
        soff[i] = (pc ^ (row & 7u)) * 8u;
    }

#pragma unroll 1
    for (int s = 0; s < 6; ++s) {
        const int src = (s >= 3) ? 1 : 0;
        const int combo = s - src * 3;               // 0 hh, 1 hl, 2 lh
        const unsigned short* Ap = src ? ((combo == 2) ? Xlo : Xhi)
                                       : ((combo == 2) ? Glo : Ghi);
        const unsigned short* Wp = src ? ((combo == 1) ? WRlo : WRhi)
                                       : ((combo == 1) ? WLlo : WLhi);
#pragma unroll 1
        for (int kt = 0; kt < 8; ++kt) {
            const int kb = kt * 64;
#pragma unroll
            for (int i = 0; i < 4; ++i) {
                const unsigned short* ga =
                    Ap + (size_t)(m0 + srow[i]) * DIM + kb + soff[i];
                const unsigned short* gw =
                    Wp + (size_t)(n0 + srow[i]) * DIM + kb + soff[i];
                uint p16 = ((uint)i * 256u + (uint)t) * 16u;
                gload16(ga, (char*)sA + p16);
                gload16(gw, (char*)sW + p16);
            }
            __syncthreads();
#pragma unroll
            for (int ks = 0; ks < 2; ++ks) {
                s16x8 af[4], wf[4];
#pragma unroll
                for (int i = 0; i < 4; ++i) {
                    int arow = wr * 64 + i * 16 + lr;
                    int off = arow * 128 + 16 * ((ks * 4 + lq) ^ (arow & 7));
                    af[i] = *(const s16x8*)((const char*)sA + off);
                }
#pragma unroll
                for (int j = 0; j < 4; ++j) {
                    int wrow = wc * 64 + j * 16 + lr;
                    int off = wrow * 128 + 16 * ((ks * 4 + lq) ^ (wrow & 7));
                    wf[j] = *(const s16x8*)((const char*)sW + off);
                }
#pragma unroll
                for (int i = 0; i < 4; ++i)
#pragma unroll
                    for (int j = 0; j < 4; ++j)
                        acc[i][j] = __builtin_amdgcn_mfma_f32_16x16x32_bf16(
                            af[i], wf[j], acc[i][j], 0, 0, 0);
            }
            __syncthreads();
        }
    }

    // epilogue: bias + relu + C store + per-row score partial
    float part[4][4];
#pragma unroll
    for (int i = 0; i < 4; ++i)
#pragma unroll
        for (int r = 0; r < 4; ++r) part[i][r] = 0.f;

#pragma unroll
    for (int i = 0; i < 4; ++i) {
        const int r0 = m0 + wr * 64 + i * 16 + lq * 4;
#pragma unroll
        for (int j = 0; j < 4; ++j) {
            const int cc = n0 + wc * 64 + j * 16 + lr;
            const float bv = bias[cc];
            const float pv = pvec[cc];
#pragma unroll
            for (int r = 0; r < 4; ++r) {
                float v = fmaxf(acc[i][j][r] + bv, 0.f);
                C[(size_t)(r0 + r) * DIM + cc] = v;
                part[i][r] = fmaf(v, pv, part[i][r]);
            }
        }
    }
#pragma unroll
    for (int o = 1; o < 16; o <<= 1)
#pragma unroll
        for (int i = 0; i < 4; ++i)
#pragma unroll
            for (int r = 0; r < 4; ++r)
                part[i][r] += __shfl_xor(part[i][r], o);
    if (lr == 0) {
#pragma unroll
        for (int i = 0; i < 4; ++i)
#pragma unroll
            for (int r = 0; r < 4; ++r)
                scp[wr * 64 + i * 16 + lq * 4 + r][wc] = part[i][r];
    }
    __syncthreads();
    if (t < 128)
        SC4[(size_t)(m0 + t) * 4 + (n0 >> 7)] = scp[t][0] + scp[t][1];
}

// ---------------------------------------------------------------------------
// 5. Fused pool + aggregation, column-sliced: block = (graph, dim-quarter).
//    scores from SC4 -> rank -> gather gated slice to LDS fp32 ->
//    X-slice write (WRITEX) -> readout slice -> [REMAP: remap+sort edges
//    (global write from slice 0 only) + aggregate from LDS -> G slice].
// ---------------------------------------------------------------------------
template<int NPER, int KEEP, bool REMAP, bool INIT, bool WRITEX>
__global__ void __launch_bounds__(256, 4)
pool_agg(const float* __restrict__ Y, const float* __restrict__ p,
         const float* __restrict__ SC4,
         unsigned short* __restrict__ Xhi, unsigned short* __restrict__ Xlo,
         const uint* __restrict__ SEp, const int* __restrict__ OFp,
         uint* __restrict__ SEn, int* __restrict__ OFn,
         unsigned short* __restrict__ Ghi, unsigned short* __restrict__ Glo,
         float* __restrict__ H)
{
    const int g  = blockIdx.x >> 2;
    const int sl = blockIdx.x & 3;
    const int c0 = sl * 128;
    const int t  = threadIdx.x;
    const int wave = t >> 6, lane = t & 63;
    __shared__ __align__(16) float xf[KEEP * 128];
    __shared__ float ssc[NPER];
    __shared__ float spnorm;
    __shared__ int   perm[KEEP];
    __shared__ float sgate[KEEP];
    __shared__ int   lnewid[NPER];

    // ---- phase A: ||p||, scores, rank ----
    if (wave == 0) {
        float v = 0.f;
#pragma unroll
        for (int i = 0; i < 8; ++i) { float x = p[lane + i * 64]; v = fmaf(x, x, v); }
#pragma unroll
        for (int off = 32; off; off >>= 1) v += __shfl_down(v, off);
        if (lane == 0) spnorm = sqrtf(v);
    }
    __syncthreads();
    if (t < NPER) {
        const float* s4 = SC4 + (size_t)(g * NPER + t) * 4;
        ssc[t] = tanhf((s4[0] + s4[1] + s4[2] + s4[3]) / spnorm);
    }
    __syncthreads();
    if (t < NPER) {
        const float s = ssc[t];
        int r = 0;
        for (int j = 0; j < NPER; ++j) {
            float sj = ssc[j];
            r += (sj > s) || (sj == s && j < t);
        }
        lnewid[t] = (r < KEEP) ? r : -1;
        if (r < KEEP) { perm[r] = t; sgate[r] = s; }
    }
    __syncthreads();

    // ---- phase B: gather gated slice to LDS fp32 ----
    for (int s = t; s < KEEP * 32; s += 256) {
        const int r = s >> 5, j4 = (s & 31) * 4;
        float4 v = *(const float4*)(Y + (size_t)(g * NPER + perm[r]) * DIM + c0 + j4);
        const float sv = sgate[r];
        v.x *= sv; v.y *= sv; v.z *= sv; v.w *= sv;
        *(float4*)&xf[r * 128 + j4] = v;
    }
    __syncthreads();

    // X-slice write (split planes)
    if (WRITEX) {
        for (int s = t; s < KEEP * 16; s += 256) {
            const int r = s >> 4, c8 = (s & 15) * 8;
            const float* src = &xf[r * 128 + c8];
            unsigned short h[8], l[8];
#pragma unroll
            for (int i = 0; i < 8; ++i) splitf(src[i], h[i], l[i]);
            uint4 Hq, Lq;
            Hq.x = pk2(h[0],h[1]); Hq.y = pk2(h[2],h[3]);
            Hq.z = pk2(h[4],h[5]); Hq.w = pk2(h[6],h[7]);
            Lq.x = pk2(l[0],l[1]); Lq.y = pk2(l[2],l[3]);
            Lq.z = pk2(l[4],l[5]); Lq.w = pk2(l[6],l[7]);
            const size_t wo = (size_t)(g * KEEP + r) * DIM + c0 + c8;
            *(uint4*)(Xhi + wo) = Hq;
            *(uint4*)(Xlo + wo) = Lq;
        }
    }
    // readout slice: thread t<128 owns dim c0+t
    if (t < 128) {
        float mx = -1e30f, sm = 0.f;
        for (int r = 0; r < KEEP; ++r) {
            float v = xf[r * 128 + t];
            mx = fmaxf(mx, v); sm += v;
        }
        const size_t o = (size_t)g * 1024 + c0 + t;
        const float me = sm / (float)KEEP;
        if (INIT) { H[o] = mx;  H[o + 512] = me; }
        else      { H[o] += mx; H[o + 512] += me; }
    }

    // ---- phase C: edge remap + sort + aggregation ----
    if constexpr (REMAP) {
        __shared__ uint  eprev[EPG];
        __shared__ uint  enew[EPG];
        __shared__ uint  esort[EPG];
        __shared__ int   cnt4[4][64];
        __shared__ int   offs[KEEP + 1];
        __shared__ int   scnt;

        if (t == 0) scnt = OFp[g * OFS + NPER];
        __syncthreads();
        const int cntp = scnt;
        for (int e = t; e < cntp; e += 256)
            eprev[e] = SEp[(size_t)g * EPG + e];
        __syncthreads();
        for (int e = t; e < cntp; e += 256) {
            const uint pk = eprev[e];
            const int ns = lnewid[pk & 0xffffu];
            const int nd = lnewid[pk >> 16];
            enew[e] = (ns >= 0 && nd >= 0)
                ? (((uint)nd << 16) | (uint)ns) : 0xFFFFFFFFu;
        }
        __syncthreads();
        {
            const int d = t & 63, q = t >> 6;
            int c = 0;
            const int e0 = q * 128;
            const int e1 = (e0 + 128 < cntp) ? e0 + 128 : cntp;
            for (int e = e0; e < e1; ++e) c += ((enew[e] >> 16) == (uint)d);
            cnt4[q][d] = c;
        }
        __syncthreads();
        if (t == 0) {
            int s = 0;
            for (int i = 0; i < KEEP; ++i) {
                offs[i] = s;
                s += cnt4[0][i] + cnt4[1][i] + cnt4[2][i] + cnt4[3][i];
            }
            offs[KEEP] = s;
        }
        __syncthreads();
        {
            const int d = t & 63, q = t >> 6;
            if (d < KEEP) {
                int w = offs[d];
                for (int q2 = 0; q2 < q; ++q2) w += cnt4[q2][d];
                const int e0 = q * 128;
                const int e1 = (e0 + 128 < cntp) ? e0 + 128 : cntp;
                for (int e = e0; e < e1; ++e)
                    if ((enew[e] >> 16) == (uint)d) esort[w++] = enew[e];
            }
        }
        __syncthreads();
        // global sorted-edge write: slice 0 only
        if (sl == 0) {
            const int cntn = offs[KEEP];
            for (int e = t; e < cntn; e += 256)
                SEn[(size_t)g * EPG + e] = esort[e];
            if (t <= KEEP) OFn[g * OFS + t] = offs[t];
        }
        // aggregation from LDS gated fp32 rows -> G slice
        const int ch = (t & 31) * 4;
        const int d0 = t >> 5;
        for (int d = d0; d < KEEP; d += 8) {
            const int cA = offs[d], cB = offs[d + 1];
            float s0 = 0.f, s1 = 0.f, s2 = 0.f, s3 = 0.f;
            for (int j = cA; j < cB; ++j) {
                const float* r = &xf[(int)(esort[j] & 0xffffu) * 128 + ch];
                s0 += r[0]; s1 += r[1]; s2 += r[2]; s3 += r[3];
            }
            const float den = fmaxf((float)(cB - cA), 1.0f);
            s0 /= den; s1 /= den; s2 /= den; s3 /= den;
            unsigned short h0,h1,h2,h3,l0,l1,l2,l3;
            splitf(s0,h0,l0); splitf(s1,h1,l1); splitf(s2,h2,l2); splitf(s3,h3,l3);
            const size_t wo = (size_t)(g * KEEP + d) * DIM + c0 + ch;
            *(uint2*)(Ghi + wo) = make_uint2(pk2(h0,h1), pk2(h2,h3));
            *(uint2*)(Glo + wo) = make_uint2(pk2(l0,l1), pk2(l2,l3));
        }
    }
}

// ---------------------------------------------------------------------------
// 6. Fused MLP head
// ---------------------------------------------------------------------------
__global__ void __launch_bounds__(256)
mlp_fused(const float* __restrict__ H,
          const float* __restrict__ lw1, const float* __restrict__ lb1,
          const float* __restrict__ lw2, const float* __restrict__ lb2,
          const float* __restrict__ lw3, const float* __restrict__ lb3,
          const float* __restrict__ lw4, const float* __restrict__ lb4,
          const float* __restrict__ lw5, const float* __restrict__ lb5,
          float* __restrict__ out)
{
    __shared__ float h0[2][1024];
    __shared__ float y1[2][512];
    __shared__ float y2[2][256];
    __shared__ float y3[2][128];
    __shared__ float y4[2][64];
    const int t = threadIdx.x;
    const int r0 = blockIdx.x * 2;

    {
        float4 a = *(const float4*)&H[(size_t)r0 * 1024 + t * 4];
        float4 b = *(const float4*)&H[(size_t)(r0 + 1) * 1024 + t * 4];
        *(float4*)&h0[0][t * 4] = a;
        *(float4*)&h0[1][t * 4] = b;
    }
    __syncthreads();
    {
        float a00 = 0.f, a01 = 0.f, a10 = 0.f, a11 = 0.f;
        const int c = t * 2;
#pragma unroll 4
        for (int k = 0; k < 1024; ++k) {
            float2 wv = *(const float2*)&lw1[(size_t)k * 512 + c];
            float x0 = h0[0][k], x1 = h0[1][k];
            a00 = fmaf(x0, wv.x, a00); a01 = fmaf(x0, wv.y, a01);
            a10 = fmaf(x1, wv.x, a10); a11 = fmaf(x1, wv.y, a11);
        }
        y1[0][c]     = fmaxf(a00 + lb1[c], 0.f);
        y1[0][c + 1] = fmaxf(a01 + lb1[c + 1], 0.f);
        y1[1][c]     = fmaxf(a10 + lb1[c], 0.f);
        y1[1][c + 1] = fmaxf(a11 + lb1[c + 1], 0.f);
    }
    __syncthreads();
    {
        float a0 = 0.f, a1 = 0.f;
#pragma unroll 4
        for (int k = 0; k < 512; ++k) {
            float wv = lw2[(size_t)k * 256 + t];
            a0 = fmaf(y1[0][k], wv, a0);
            a1 = fmaf(y1[1][k], wv, a1);
        }
        y2[0][t] = fmaxf(a0 + lb2[t], 0.f);
        y2[1][t] = fmaxf(a1 + lb2[t], 0.f);
    }
    __syncthreads();
    if (t < 128) {
        float a0 = 0.f, a1 = 0.f;
#pragma unroll 4
        for (int k = 0; k < 256; ++k) {
            float wv = lw3[(size_t)k * 128 + t];
            a0 = fmaf(y2[0][k], wv, a0);
            a1 = fmaf(y2[1][k], wv, a1);
        }
        y3[0][t] = fmaxf(a0 + lb3[t], 0.f);
        y3[1][t] = fmaxf(a1 + lb3[t], 0.f);
    }
    __syncthreads();
    if (t < 64) {
        float a0 = 0.f, a1 = 0.f;
#pragma unroll 4
        for (int k = 0; k < 128; ++k) {
            float wv = lw4[(size_t)k * 64 + t];
            a0 = fmaf(y3[0][k], wv, a0);
            a1 = fmaf(y3[1][k], wv, a1);
        }
        y4[0][t] = fmaxf(a0 + lb4[t], 0.f);
        y4[1][t] = fmaxf(a1 + lb4[t], 0.f);
    }
    __syncthreads();
    const int wv = t >> 6, ln = t & 63;
    if (wv < 2) {
        float v = y4[wv][ln] * lw5[ln];
#pragma unroll
        for (int off = 32; off; off >>= 1) v += __shfl_down(v, off);
        if (ln == 0) out[r0 + wv] = 1.f / (1.f + expf(-(v + lb5[0])));
    }
}

// ---------------------------------------------------------------------------
extern "C" void kernel_launch(void* const* d_in, const int* in_sizes, int n_in,
                              void* d_out, int out_size, void* d_ws, size_t ws_size,
                              hipStream_t stream)
{
    const int*   x_ids = (const int*)d_in[0];
    const int*   esrc  = (const int*)d_in[1];
    const int*   edst  = (const int*)d_in[2];
    const float* emb   = (const float*)d_in[3];
    const float* w1l = (const float*)d_in[4],  *b1l = (const float*)d_in[5],  *w1r = (const float*)d_in[6];
    const float* w2l = (const float*)d_in[7],  *b2l = (const float*)d_in[8],  *w2r = (const float*)d_in[9];
    const float* w3l = (const float*)d_in[10], *b3l = (const float*)d_in[11], *w3r = (const float*)d_in[12];
    const float* p1  = (const float*)d_in[13];
    const float* p2  = (const float*)d_in[14];
    const float* p3  = (const float*)d_in[15];
    const float* lw1 = (const float*)d_in[16], *lb1 = (const float*)d_in[17];
    const float* lw2 = (const float*)d_in[18], *lb2 = (const float*)d_in[19];
    const float* lw3 = (const float*)d_in[20], *lb3 = (const float*)d_in[21];
    const float* lw4 = (const float*)d_in[22], *lb4 = (const float*)d_in[23];
    const float* lw5 = (const float*)d_in[24], *lb5 = (const float*)d_in[25];
    float* out = (float*)d_out;

    // ---- workspace layout ----
    const size_t PL = (size_t)65536 * DIM;
    unsigned short* Xhi = (unsigned short*)d_ws;
    unsigned short* Xlo = Xhi + PL;
    unsigned short* Ghi = Xlo + PL;
    unsigned short* Glo = Ghi + PL;
    float* Cc  = (float*)(Glo + PL);
    float* H   = Cc + PL;
    float* SC4 = H + (size_t)1024 * 1024;
    uint*  SE1 = (uint*)(SC4 + (size_t)65536 * 4);
    uint*  SE2 = SE1 + ETOT;
    uint*  SE3 = SE2 + ETOT;
    int*   OF1 = (int*)(SE3 + ETOT);
    int*   OF2 = OF1 + BG * OFS;
    int*   OF3 = OF2 + BG * OFS;
    unsigned short* WT = (unsigned short*)(OF3 + BG * OFS);
    const size_t WSZ = (size_t)DIM * DIM;
    unsigned short *w1lh = WT + 0*WSZ,  *w1ll = WT + 1*WSZ;
    unsigned short *w1rh = WT + 2*WSZ,  *w1rl = WT + 3*WSZ;
    unsigned short *w2lh = WT + 4*WSZ,  *w2ll = WT + 5*WSZ;
    unsigned short *w2rh = WT + 6*WSZ,  *w2rl = WT + 7*WSZ;
    unsigned short *w3lh = WT + 8*WSZ,  *w3ll = WT + 9*WSZ;
    unsigned short *w3rh = WT + 10*WSZ, *w3rl = WT + 11*WSZ;

    // ---- weight conversion ----
    WPtrs wp;
    wp.w[0] = w1l; wp.w[1] = w1r; wp.w[2] = w2l;
    wp.w[3] = w2r; wp.w[4] = w3l; wp.w[5] = w3r;
    split_wT_all<<<6 * 256, 256, 0, stream>>>(wp, WT);

    // ---- layer 1 ----
    sort_edges1<<<BG, 256, 0, stream>>>(esrc, edst, SE1, OF1);
    gather_agg<<<BG * 4, 256, 0, stream>>>(x_ids, emb, SE1, OF1,
                                           Xhi, Xlo, Ghi, Glo);
    gemm_sage<<<(65536/128)*4, 256, 0, stream>>>(Ghi, Glo, w1lh, w1ll,
                                                 Xhi, Xlo, w1rh, w1rl,
                                                 b1l, p1, Cc, SC4, 65536);
    pool_agg<64, KP1, true, true, true><<<BG * 4, 256, 0, stream>>>(
        Cc, p1, SC4, Xhi, Xlo, SE1, OF1, SE2, OF2, Ghi, Glo, H);

    // ---- layer 2 ----
    gemm_sage<<<(53248/128)*4, 256, 0, stream>>>(Ghi, Glo, w2lh, w2ll,
                                                 Xhi, Xlo, w2rh, w2rl,
                                                 b2l, p2, Cc, SC4, 53248);
    pool_agg<KP1, KP2, true, false, true><<<BG * 4, 256, 0, stream>>>(
        Cc, p2, SC4, Xhi, Xlo, SE2, OF2, SE3, OF3, Ghi, Glo, H);

    // ---- layer 3 ----
    gemm_sage<<<(43008/128)*4, 256, 0, stream>>>(Ghi, Glo, w3lh, w3ll,
                                                 Xhi, Xlo, w3rh, w3rl,
                                                 b3l, p3, Cc, SC4, 43008);
    pool_agg<KP2, KP3, false, false, false><<<BG * 4, 256, 0, stream>>>(
        Cc, p3, SC4, nullptr, nullptr, nullptr, nullptr, nullptr, nullptr,
        nullptr, nullptr, H);

    // ---- fused MLP head ----
    mlp_fused<<<512, 256, 0, stream>>>(H, lw1, lb1, lw2, lb2, lw3, lb3,
                                       lw4, lb4, lw5, lb5, out);
}

// Round 13
// 1151.671 us; speedup vs baseline: 1.0541x; 1.0541x over previous
//
#include <hip/hip_runtime.h>
#include <math.h>

// Problem constants
#define BG 1024
#define EPG 512
#define ETOT (BG*EPG)
#define DIM 512
#define KP1 52
#define KP2 42
#define KP3 34
#define OFS 80   // stride of per-graph offset tables

typedef unsigned int uint;
typedef short s16x8 __attribute__((ext_vector_type(8)));
typedef float f32x4 __attribute__((ext_vector_type(4)));

// ---------------- bf16 split helpers ----------------
__device__ __forceinline__ unsigned short f2b(float x) {
    uint u = __float_as_uint(x);
    u = u + 0x7fffu + ((u >> 16) & 1u);
    return (unsigned short)(u >> 16);
}
__device__ __forceinline__ float b2f(unsigned short h) {
    return __uint_as_float(((uint)h) << 16);
}
__device__ __forceinline__ void splitf(float x, unsigned short& h, unsigned short& l) {
    h = f2b(x);
    l = f2b(x - b2f(h));
}
__device__ __forceinline__ uint pk2(unsigned short a, unsigned short b) {
    return (uint)a | ((uint)b << 16);
}

__device__ __forceinline__ void gload16(const void* g, void* l) {
    __builtin_amdgcn_global_load_lds(
        (const __attribute__((address_space(1))) void*)g,
        (__attribute__((address_space(3))) void*)l, 16, 0, 0);
}

// ---------------------------------------------------------------------------
// 1. Weight convert, all 6 weights in one launch
// ---------------------------------------------------------------------------
struct WPtrs { const float* w[6]; };

__global__ void __launch_bounds__(256)
split_wT_all(WPtrs p, unsigned short* __restrict__ WT)
{
    const int wi = blockIdx.x >> 8;
    const int bb = blockIdx.x & 255;
    const float* W = p.w[wi];
    unsigned short* Thi = WT + (size_t)(2 * wi) * DIM * DIM;
    unsigned short* Tlo = Thi + (size_t)DIM * DIM;
    __shared__ float tl[32][33];
    const int t  = threadIdx.x;
    const int bx = bb & 15;
    const int by = bb >> 4;
    const int lx = t & 31, ly = t >> 5;
    for (int r = ly; r < 32; r += 8)
        tl[r][lx] = W[(size_t)(by*32 + r) * DIM + bx*32 + lx];
    __syncthreads();
    for (int r = ly; r < 32; r += 8) {
        float v = tl[lx][r];
        unsigned short h, l; splitf(v, h, l);
        size_t o = (size_t)(bx*32 + r) * DIM + by*32 + lx;
        Thi[o] = h; Tlo[o] = l;
    }
}

// ---------------------------------------------------------------------------
// 2. Layer-1 edge sort: counting sort by local dst, packed (dst<<16|src)
// ---------------------------------------------------------------------------
__global__ void __launch_bounds__(256)
sort_edges1(const int* __restrict__ esrc, const int* __restrict__ edst,
            uint* __restrict__ SE, int* __restrict__ OF)
{
    const int g = blockIdx.x;
    const int t = threadIdx.x;
    __shared__ int ld[EPG];
    __shared__ int ls[EPG];
    __shared__ int cnt4[4][64];
    __shared__ int offs[65];
    const int eb = g * EPG;
    for (int e = t; e < EPG; e += 256) {
        ld[e] = edst[eb + e] - g * 64;
        ls[e] = esrc[eb + e] - g * 64;
    }
    __syncthreads();
    {
        const int d = t & 63, q = t >> 6;
        int c = 0;
        for (int e = q * 128; e < q * 128 + 128; ++e) c += (ld[e] == d);
        cnt4[q][d] = c;
    }
    __syncthreads();
    if (t == 0) {
        int s = 0;
        for (int i = 0; i < 64; ++i) {
            offs[i] = s;
            s += cnt4[0][i] + cnt4[1][i] + cnt4[2][i] + cnt4[3][i];
        }
        offs[64] = s;
    }
    __syncthreads();
    {
        const int d = t & 63, q = t >> 6;
        int w = offs[d];
        for (int q2 = 0; q2 < q; ++q2) w += cnt4[q2][d];
        for (int e = q * 128; e < q * 128 + 128; ++e)
            if (ld[e] == d) SE[(size_t)g * EPG + (w++)] = ((uint)d << 16) | (uint)ls[e];
    }
    if (t <= 64) OF[g * OFS + t] = offs[t];
}

// ---------------------------------------------------------------------------
// 3. Fused gather + split + layer-1 aggregation, column-sliced.
// ---------------------------------------------------------------------------
__global__ void __launch_bounds__(256, 4)
gather_agg(const int* __restrict__ ids, const float* __restrict__ emb,
           const uint* __restrict__ SE, const int* __restrict__ OF,
           unsigned short* __restrict__ Xhi, unsigned short* __restrict__ Xlo,
           unsigned short* __restrict__ Ghi, unsigned short* __restrict__ Glo)
{
    const int g  = blockIdx.x >> 2;
    const int c0 = (blockIdx.x & 3) * 128;
    const int t  = threadIdx.x;
    __shared__ __align__(16) float xf[64 * 128];   // 32 KB
    __shared__ int lid[64];
    __shared__ uint el[EPG];
    __shared__ int offs[65];

    if (t < 64) lid[t] = ids[g * 64 + t];
    if (t >= 128 && t < 128 + 65) offs[t - 128] = OF[g * OFS + (t - 128)];
    __syncthreads();

    for (int s = t; s < 64 * 32; s += 256) {
        const int row = s >> 5;
        const int c4  = (s & 31) * 4;
        ((float4*)xf)[s] =
            *(const float4*)(emb + (size_t)lid[row] * DIM + c0 + c4);
    }
    const int cnt = offs[64];
    for (int e = t; e < cnt; e += 256) el[e] = SE[(size_t)g * EPG + e];
    __syncthreads();

    for (int s = t; s < 64 * 16; s += 256) {
        const int row = s >> 4;
        const int c8  = (s & 15) * 8;
        const float* src = &xf[row * 128 + c8];
        unsigned short h[8], l[8];
#pragma unroll
        for (int i = 0; i < 8; ++i) splitf(src[i], h[i], l[i]);
        uint4 Hq, Lq;
        Hq.x = pk2(h[0],h[1]); Hq.y = pk2(h[2],h[3]);
        Hq.z = pk2(h[4],h[5]); Hq.w = pk2(h[6],h[7]);
        Lq.x = pk2(l[0],l[1]); Lq.y = pk2(l[2],l[3]);
        Lq.z = pk2(l[4],l[5]); Lq.w = pk2(l[6],l[7]);
        const size_t wo = (size_t)(g * 64 + row) * DIM + c0 + c8;
        *(uint4*)(Xhi + wo) = Hq;
        *(uint4*)(Xlo + wo) = Lq;
    }

    const int ch = (t & 31) * 4;
    const int d0 = t >> 5;
    for (int d = d0; d < 64; d += 8) {
        const int cA = offs[d], cB = offs[d + 1];
        float s0 = 0.f, s1 = 0.f, s2 = 0.f, s3 = 0.f;
        for (int j = cA; j < cB; ++j) {
            const float* r = &xf[(int)(el[j] & 0xffffu) * 128 + ch];
            s0 += r[0]; s1 += r[1]; s2 += r[2]; s3 += r[3];
        }
        const float den = fmaxf((float)(cB - cA), 1.0f);
        s0 /= den; s1 /= den; s2 /= den; s3 /= den;
        unsigned short h0,h1,h2,h3,l0,l1,l2,l3;
        splitf(s0,h0,l0); splitf(s1,h1,l1); splitf(s2,h2,l2); splitf(s3,h3,l3);
        const size_t wo = (size_t)(g * 64 + d) * DIM + c0 + ch;
        *(uint2*)(Ghi + wo) = make_uint2(pk2(h0,h1), pk2(h2,h3));
        *(uint2*)(Glo + wo) = make_uint2(pk2(l0,l1), pk2(l2,l3));
    }
}

// ---------------------------------------------------------------------------
// 4. Mean aggregation from pre-sorted edge lists, column-sliced (layers 2/3)
// ---------------------------------------------------------------------------
template<int NPER>
__global__ void __launch_bounds__(256, 4)
agg_sorted(const unsigned short* __restrict__ Xhi, const unsigned short* __restrict__ Xlo,
           const uint* __restrict__ SE, const int* __restrict__ OF,
           unsigned short* __restrict__ Ghi, unsigned short* __restrict__ Glo)
{
    const int g  = blockIdx.x >> 2;
    const int c0 = (blockIdx.x & 3) * 128;
    const int t  = threadIdx.x;
    __shared__ __align__(16) unsigned short xs[NPER * 256];
    __shared__ uint el[EPG];
    __shared__ int offs[NPER + 1];

    for (int s = t; s < NPER * 32; s += 256) {
        const int row  = s >> 5;
        const int half = (s >> 4) & 1;
        const int c8   = (s & 15) * 8;
        const unsigned short* src =
            (half ? Xlo : Xhi) + (size_t)(g * NPER + row) * DIM + c0 + c8;
        gload16(src, (char*)xs + (size_t)s * 16);
    }
    if (t <= NPER) offs[t] = OF[g * OFS + t];
    __syncthreads();
    const int cnt = offs[NPER];
    for (int e = t; e < cnt; e += 256) el[e] = SE[(size_t)g * EPG + e];
    __syncthreads();

    const int ch = (t & 31) * 4;
    const int d0 = t >> 5;
    for (int d = d0; d < NPER; d += 8) {
        const int cA = offs[d], cB = offs[d + 1];
        float s0 = 0.f, s1 = 0.f, s2 = 0.f, s3 = 0.f;
        for (int j = cA; j < cB; ++j) {
            const int base = (int)(el[j] & 0xffffu) * 256 + ch;
            ushort4 h = *(const ushort4*)&xs[base];
            ushort4 l = *(const ushort4*)&xs[base + 128];
            s0 += b2f(h.x) + b2f(l.x);
            s1 += b2f(h.y) + b2f(l.y);
            s2 += b2f(h.z) + b2f(l.z);
            s3 += b2f(h.w) + b2f(l.w);
        }
        const float den = fmaxf((float)(cB - cA), 1.0f);
        s0 /= den; s1 /= den; s2 /= den; s3 /= den;
        unsigned short h0,h1,h2,h3,l0,l1,l2,l3;
        splitf(s0,h0,l0); splitf(s1,h1,l1); splitf(s2,h2,l2); splitf(s3,h3,l3);
        const size_t wo = (size_t)(g * NPER + d) * DIM + c0 + ch;
        *(uint2*)(Ghi + wo) = make_uint2(pk2(h0,h1), pk2(h2,h3));
        *(uint2*)(Glo + wo) = make_uint2(pk2(l0,l1), pk2(l2,l3));
    }
}

// ---------------------------------------------------------------------------
// 5. Split-bf16 MFMA GEMM (round-8 version: proven local optimum)
//    + fused per-row score partials (y . p per N-block)
// ---------------------------------------------------------------------------
__global__ void __launch_bounds__(256)
gemm_sage(const unsigned short* __restrict__ Ghi, const unsigned short* __restrict__ Glo,
          const unsigned short* __restrict__ WLhi, const unsigned short* __restrict__ WLlo,
          const unsigned short* __restrict__ Xhi, const unsigned short* __restrict__ Xlo,
          const unsigned short* __restrict__ WRhi, const unsigned short* __restrict__ WRlo,
          const float* __restrict__ bias, const float* __restrict__ pvec,
          float* __restrict__ C, float* __restrict__ SC4, int M)
{
    __shared__ unsigned short sA[128 * 64];
    __shared__ unsigned short sW[128 * 64];
    __shared__ float scp[128][2];

    const int t = threadIdx.x;
    const uint nwg = gridDim.x;
    const uint q8  = nwg >> 3;
    const uint bid = blockIdx.x;
    const uint sw  = (bid & 7) * q8 + (bid >> 3);
    const int  m0  = (int)(sw >> 2) * 128;
    const int  n0  = (int)(sw & 3) * 128;

    const int l  = t & 63;
    const int w  = t >> 6;
    const int wr = w >> 1;
    const int wc = w & 1;
    const int lr = l & 15;
    const int lq = l >> 4;

    f32x4 acc[4][4];
#pragma unroll
    for (int i = 0; i < 4; ++i)
#pragma unroll
        for (int j = 0; j < 4; ++j) acc[i][j] = (f32x4){0.f, 0.f, 0.f, 0.f};

    uint srow[4], soff[4];
#pragma unroll
    for (int i = 0; i < 4; ++i) {
        uint p = (uint)i * 256u + (uint)t;
        uint row = p >> 3, pc = p & 7;
        srow[i] = row;
        soff[i] = (pc ^ (row & 7u)) * 8u;
    }

#pragma unroll 1
    for (int s = 0; s < 6; ++s) {
        const int src = (s >= 3) ? 1 : 0;
        const int combo = s - src * 3;               // 0 hh, 1 hl, 2 lh
        const unsigned short* Ap = src ? ((combo == 2) ? Xlo : Xhi)
                                       : ((combo == 2) ? Glo : Ghi);
        const unsigned short* Wp = src ? ((combo == 1) ? WRlo : WRhi)
                                       : ((combo == 1) ? WLlo : WLhi);
#pragma unroll 1
        for (int kt = 0; kt < 8; ++kt) {
            const int kb = kt * 64;
#pragma unroll
            for (int i = 0; i < 4; ++i) {
                const unsigned short* ga =
                    Ap + (size_t)(m0 + srow[i]) * DIM + kb + soff[i];
                const unsigned short* gw =
                    Wp + (size_t)(n0 + srow[i]) * DIM + kb + soff[i];
                uint p16 = ((uint)i * 256u + (uint)t) * 16u;
                gload16(ga, (char*)sA + p16);
                gload16(gw, (char*)sW + p16);
            }
            __syncthreads();
#pragma unroll
            for (int ks = 0; ks < 2; ++ks) {
                s16x8 af[4], wf[4];
#pragma unroll
                for (int i = 0; i < 4; ++i) {
                    int arow = wr * 64 + i * 16 + lr;
                    int off = arow * 128 + 16 * ((ks * 4 + lq) ^ (arow & 7));
                    af[i] = *(const s16x8*)((const char*)sA + off);
                }
#pragma unroll
                for (int j = 0; j < 4; ++j) {
                    int wrow = wc * 64 + j * 16 + lr;
                    int off = wrow * 128 + 16 * ((ks * 4 + lq) ^ (wrow & 7));
                    wf[j] = *(const s16x8*)((const char*)sW + off);
                }
#pragma unroll
                for (int i = 0; i < 4; ++i)
#pragma unroll
                    for (int j = 0; j < 4; ++j)
                        acc[i][j] = __builtin_amdgcn_mfma_f32_16x16x32_bf16(
                            af[i], wf[j], acc[i][j], 0, 0, 0);
            }
            __syncthreads();
        }
    }

    // epilogue: bias + relu + C store + per-row score partial
    float part[4][4];
#pragma unroll
    for (int i = 0; i < 4; ++i)
#pragma unroll
        for (int r = 0; r < 4; ++r) part[i][r] = 0.f;

#pragma unroll
    for (int i = 0; i < 4; ++i) {
        const int r0 = m0 + wr * 64 + i * 16 + lq * 4;
#pragma unroll
        for (int j = 0; j < 4; ++j) {
            const int cc = n0 + wc * 64 + j * 16 + lr;
            const float bv = bias[cc];
            const float pv = pvec[cc];
#pragma unroll
            for (int r = 0; r < 4; ++r) {
                float v = fmaxf(acc[i][j][r] + bv, 0.f);
                C[(size_t)(r0 + r) * DIM + cc] = v;
                part[i][r] = fmaf(v, pv, part[i][r]);
            }
        }
    }
#pragma unroll
    for (int o = 1; o < 16; o <<= 1)
#pragma unroll
        for (int i = 0; i < 4; ++i)
#pragma unroll
            for (int r = 0; r < 4; ++r)
                part[i][r] += __shfl_xor(part[i][r], o);
    if (lr == 0) {
#pragma unroll
        for (int i = 0; i < 4; ++i)
#pragma unroll
            for (int r = 0; r < 4; ++r)
                scp[wr * 64 + i * 16 + lq * 4 + r][wc] = part[i][r];
    }
    __syncthreads();
    if (t < 128)
        SC4[(size_t)(m0 + t) * 4 + (n0 >> 7)] = scp[t][0] + scp[t][1];
}

// ---------------------------------------------------------------------------
// 6. Fused pool: scores from SC4 + rank + gate/split-write + readout
//    + sorted-edge remap for next layer
// ---------------------------------------------------------------------------
template<int NPER, int KEEP, bool REMAP, bool INIT>
__global__ void __launch_bounds__(256)
pool_fused(const float* __restrict__ Y, const float* __restrict__ p,
           const float* __restrict__ SC4,
           unsigned short* __restrict__ Xhi, unsigned short* __restrict__ Xlo,
           const uint* __restrict__ SEp, const int* __restrict__ OFp,
           uint* __restrict__ SEn, int* __restrict__ OFn,
           float* __restrict__ H)
{
    const int g = blockIdx.x;
    const int t = threadIdx.x;
    const int wave = t >> 6, lane = t & 63;
    __shared__ float ssc[NPER];
    __shared__ float spnorm;
    __shared__ int   perm[KEEP];
    __shared__ float sgate[KEEP];
    __shared__ int   lnewid[NPER];
    __shared__ uint  eprev[EPG];
    __shared__ uint  enew[EPG];
    __shared__ int   cnt4[4][64];
    __shared__ int   offs[KEEP + 1];

    if (wave == 0) {
        float v = 0.f;
#pragma unroll
        for (int i = 0; i < 8; ++i) { float x = p[lane + i * 64]; v = fmaf(x, x, v); }
#pragma unroll
        for (int off = 32; off; off >>= 1) v += __shfl_down(v, off);
        if (lane == 0) spnorm = sqrtf(v);
    }
    __syncthreads();
    if (t < NPER) {
        const float* s4 = SC4 + (size_t)(g * NPER + t) * 4;
        float raw = s4[0] + s4[1] + s4[2] + s4[3];
        ssc[t] = tanhf(raw / spnorm);
    }
    __syncthreads();
    if (t < NPER) {
        const float s = ssc[t];
        int r = 0;
        for (int j = 0; j < NPER; ++j) {
            float sj = ssc[j];
            r += (sj > s) || (sj == s && j < t);
        }
        lnewid[t] = (r < KEEP) ? r : -1;
        if (r < KEEP) { perm[r] = t; sgate[r] = s; }
    }
    __syncthreads();

    float mx0 = -1e30f, mx1 = -1e30f, sm0 = 0.f, sm1 = 0.f;
    for (int r = 0; r < KEEP; ++r) {
        const float2 v = ((const float2*)(Y + (size_t)(g * NPER + perm[r]) * DIM))[t];
        const float sv = sgate[r];
        float a = v.x * sv, b = v.y * sv;
        mx0 = fmaxf(mx0, a); mx1 = fmaxf(mx1, b);
        sm0 += a; sm1 += b;
        unsigned short ha, la, hb, lb;
        splitf(a, ha, la); splitf(b, hb, lb);
        size_t o = (size_t)(g * KEEP + r) * DIM + 2 * t;
        *(uint*)(Xhi + o) = pk2(ha, hb);
        *(uint*)(Xlo + o) = pk2(la, lb);
    }
    {
        const size_t o = (size_t)g * 1024;
        const float me0 = sm0 / (float)KEEP, me1 = sm1 / (float)KEEP;
        if (INIT) {
            H[o + 2*t]       = mx0; H[o + 2*t + 1]       = mx1;
            H[o + 512 + 2*t] = me0; H[o + 512 + 2*t + 1] = me1;
        } else {
            H[o + 2*t]       += mx0; H[o + 2*t + 1]       += mx1;
            H[o + 512 + 2*t] += me0; H[o + 512 + 2*t + 1] += me1;
        }
    }

    if constexpr (REMAP) {
        const int cntp = OFp[g * OFS + NPER];
        for (int e = t; e < cntp; e += 256)
            eprev[e] = SEp[(size_t)g * EPG + e];
        __syncthreads();
        for (int e = t; e < cntp; e += 256) {
            const uint pk = eprev[e];
            const int ns = lnewid[pk & 0xffffu];
            const int nd = lnewid[pk >> 16];
            enew[e] = (ns >= 0 && nd >= 0)
                ? (((uint)nd << 16) | (uint)ns) : 0xFFFFFFFFu;
        }
        __syncthreads();
        {
            const int d = t & 63, q = t >> 6;
            int c = 0;
            const int e0 = q * 128;
            const int e1 = (e0 + 128 < cntp) ? e0 + 128 : cntp;
            for (int e = e0; e < e1; ++e) c += ((enew[e] >> 16) == (uint)d);
            cnt4[q][d] = c;
        }
        __syncthreads();
        if (t == 0) {
            int s = 0;
            for (int i = 0; i < KEEP; ++i) {
                offs[i] = s;
                s += cnt4[0][i] + cnt4[1][i] + cnt4[2][i] + cnt4[3][i];
            }
            offs[KEEP] = s;
        }
        __syncthreads();
        {
            const int d = t & 63, q = t >> 6;
            if (d < KEEP) {
                int w = offs[d];
                for (int q2 = 0; q2 < q; ++q2) w += cnt4[q2][d];
                const int e0 = q * 128;
                const int e1 = (e0 + 128 < cntp) ? e0 + 128 : cntp;
                for (int e = e0; e < e1; ++e)
                    if ((enew[e] >> 16) == (uint)d)
                        SEn[(size_t)g * EPG + (w++)] = enew[e];
            }
        }
        if (t <= KEEP) OFn[g * OFS + t] = offs[t];
    }
}

// ---------------------------------------------------------------------------
// 7. Fused MLP head
// ---------------------------------------------------------------------------
__global__ void __launch_bounds__(256)
mlp_fused(const float* __restrict__ H,
          const float* __restrict__ lw1, const float* __restrict__ lb1,
          const float* __restrict__ lw2, const float* __restrict__ lb2,
          const float* __restrict__ lw3, const float* __restrict__ lb3,
          const float* __restrict__ lw4, const float* __restrict__ lb4,
          const float* __restrict__ lw5, const float* __restrict__ lb5,
          float* __restrict__ out)
{
    __shared__ float h0[2][1024];
    __shared__ float y1[2][512];
    __shared__ float y2[2][256];
    __shared__ float y3[2][128];
    __shared__ float y4[2][64];
    const int t = threadIdx.x;
    const int r0 = blockIdx.x * 2;

    {
        float4 a = *(const float4*)&H[(size_t)r0 * 1024 + t * 4];
        float4 b = *(const float4*)&H[(size_t)(r0 + 1) * 1024 + t * 4];
        *(float4*)&h0[0][t * 4] = a;
        *(float4*)&h0[1][t * 4] = b;
    }
    __syncthreads();
    {
        float a00 = 0.f, a01 = 0.f, a10 = 0.f, a11 = 0.f;
        const int c = t * 2;
#pragma unroll 4
        for (int k = 0; k < 1024; ++k) {
            float2 wv = *(const float2*)&lw1[(size_t)k * 512 + c];
            float x0 = h0[0][k], x1 = h0[1][k];
            a00 = fmaf(x0, wv.x, a00); a01 = fmaf(x0, wv.y, a01);
            a10 = fmaf(x1, wv.x, a10); a11 = fmaf(x1, wv.y, a11);
        }
        y1[0][c]     = fmaxf(a00 + lb1[c], 0.f);
        y1[0][c + 1] = fmaxf(a01 + lb1[c + 1], 0.f);
        y1[1][c]     = fmaxf(a10 + lb1[c], 0.f);
        y1[1][c + 1] = fmaxf(a11 + lb1[c + 1], 0.f);
    }
    __syncthreads();
    {
        float a0 = 0.f, a1 = 0.f;
#pragma unroll 4
        for (int k = 0; k < 512; ++k) {
            float wv = lw2[(size_t)k * 256 + t];
            a0 = fmaf(y1[0][k], wv, a0);
            a1 = fmaf(y1[1][k], wv, a1);
        }
        y2[0][t] = fmaxf(a0 + lb2[t], 0.f);
        y2[1][t] = fmaxf(a1 + lb2[t], 0.f);
    }
    __syncthreads();
    if (t < 128) {
        float a0 = 0.f, a1 = 0.f;
#pragma unroll 4
        for (int k = 0; k < 256; ++k) {
            float wv = lw3[(size_t)k * 128 + t];
            a0 = fmaf(y2[0][k], wv, a0);
            a1 = fmaf(y2[1][k], wv, a1);
        }
        y3[0][t] = fmaxf(a0 + lb3[t], 0.f);
        y3[1][t] = fmaxf(a1 + lb3[t], 0.f);
    }
    __syncthreads();
    if (t < 64) {
        float a0 = 0.f, a1 = 0.f;
#pragma unroll 4
        for (int k = 0; k < 128; ++k) {
            float wv = lw4[(size_t)k * 64 + t];
            a0 = fmaf(y3[0][k], wv, a0);
            a1 = fmaf(y3[1][k], wv, a1);
        }
        y4[0][t] = fmaxf(a0 + lb4[t], 0.f);
        y4[1][t] = fmaxf(a1 + lb4[t], 0.f);
    }
    __syncthreads();
    const int wv = t >> 6, ln = t & 63;
    if (wv < 2) {
        float v = y4[wv][ln] * lw5[ln];
#pragma unroll
        for (int off = 32; off; off >>= 1) v += __shfl_down(v, off);
        if (ln == 0) out[r0 + wv] = 1.f / (1.f + expf(-(v + lb5[0])));
    }
}

// ---------------------------------------------------------------------------
extern "C" void kernel_launch(void* const* d_in, const int* in_sizes, int n_in,
                              void* d_out, int out_size, void* d_ws, size_t ws_size,
                              hipStream_t stream)
{
    const int*   x_ids = (const int*)d_in[0];
    const int*   esrc  = (const int*)d_in[1];
    const int*   edst  = (const int*)d_in[2];
    const float* emb   = (const float*)d_in[3];
    const float* w1l = (const float*)d_in[4],  *b1l = (const float*)d_in[5],  *w1r = (const float*)d_in[6];
    const float* w2l = (const float*)d_in[7],  *b2l = (const float*)d_in[8],  *w2r = (const float*)d_in[9];
    const float* w3l = (const float*)d_in[10], *b3l = (const float*)d_in[11], *w3r = (const float*)d_in[12];
    const float* p1  = (const float*)d_in[13];
    const float* p2  = (const float*)d_in[14];
    const float* p3  = (const float*)d_in[15];
    const float* lw1 = (const float*)d_in[16], *lb1 = (const float*)d_in[17];
    const float* lw2 = (const float*)d_in[18], *lb2 = (const float*)d_in[19];
    const float* lw3 = (const float*)d_in[20], *lb3 = (const float*)d_in[21];
    const float* lw4 = (const float*)d_in[22], *lb4 = (const float*)d_in[23];
    const float* lw5 = (const float*)d_in[24], *lb5 = (const float*)d_in[25];
    float* out = (float*)d_out;

    // ---- workspace layout ----
    const size_t PL = (size_t)65536 * DIM;
    unsigned short* Xhi = (unsigned short*)d_ws;
    unsigned short* Xlo = Xhi + PL;
    unsigned short* Ghi = Xlo + PL;
    unsigned short* Glo = Ghi + PL;
    float* Cc  = (float*)(Glo + PL);
    float* H   = Cc + PL;
    float* SC4 = H + (size_t)1024 * 1024;
    uint*  SE1 = (uint*)(SC4 + (size_t)65536 * 4);
    uint*  SE2 = SE1 + ETOT;
    uint*  SE3 = SE2 + ETOT;
    int*   OF1 = (int*)(SE3 + ETOT);
    int*   OF2 = OF1 + BG * OFS;
    int*   OF3 = OF2 + BG * OFS;
    unsigned short* WT = (unsigned short*)(OF3 + BG * OFS);
    const size_t WSZ = (size_t)DIM * DIM;
    unsigned short *w1lh = WT + 0*WSZ,  *w1ll = WT + 1*WSZ;
    unsigned short *w1rh = WT + 2*WSZ,  *w1rl = WT + 3*WSZ;
    unsigned short *w2lh = WT + 4*WSZ,  *w2ll = WT + 5*WSZ;
    unsigned short *w2rh = WT + 6*WSZ,  *w2rl = WT + 7*WSZ;
    unsigned short *w3lh = WT + 8*WSZ,  *w3ll = WT + 9*WSZ;
    unsigned short *w3rh = WT + 10*WSZ, *w3rl = WT + 11*WSZ;

    // ---- weight conversion ----
    WPtrs wp;
    wp.w[0] = w1l; wp.w[1] = w1r; wp.w[2] = w2l;
    wp.w[3] = w2r; wp.w[4] = w3l; wp.w[5] = w3r;
    split_wT_all<<<6 * 256, 256, 0, stream>>>(wp, WT);

    // ---- layer 1 ----
    sort_edges1<<<BG, 256, 0, stream>>>(esrc, edst, SE1, OF1);
    gather_agg<<<BG * 4, 256, 0, stream>>>(x_ids, emb, SE1, OF1,
                                           Xhi, Xlo, Ghi, Glo);
    gemm_sage<<<(65536/128)*4, 256, 0, stream>>>(Ghi, Glo, w1lh, w1ll,
                                                 Xhi, Xlo, w1rh, w1rl,
                                                 b1l, p1, Cc, SC4, 65536);
    pool_fused<64, KP1, true, true><<<BG, 256, 0, stream>>>(
        Cc, p1, SC4, Xhi, Xlo, SE1, OF1, SE2, OF2, H);

    // ---- layer 2 ----
    agg_sorted<KP1><<<BG * 4, 256, 0, stream>>>(Xhi, Xlo, SE2, OF2, Ghi, Glo);
    gemm_sage<<<(53248/128)*4, 256, 0, stream>>>(Ghi, Glo, w2lh, w2ll,
                                                 Xhi, Xlo, w2rh, w2rl,
                                                 b2l, p2, Cc, SC4, 53248);
    pool_fused<KP1, KP2, true, false><<<BG, 256, 0, stream>>>(
        Cc, p2, SC4, Xhi, Xlo, SE2, OF2, SE3, OF3, H);

    // ---- layer 3 ----
    agg_sorted<KP2><<<BG * 4, 256, 0, stream>>>(Xhi, Xlo, SE3, OF3, Ghi, Glo);
    gemm_sage<<<(43008/128)*4, 256, 0, stream>>>(Ghi, Glo, w3lh, w3ll,
                                                 Xhi, Xlo, w3rh, w3rl,
                                                 b3l, p3, Cc, SC4, 43008);
    pool_fused<KP2, KP3, false, false><<<BG, 256, 0, stream>>>(
        Cc, p3, SC4, Xhi, Xlo, nullptr, nullptr, nullptr, nullptr, H);

    // ---- fused MLP head ----
    mlp_fused<<<512, 256, 0, stream>>>(H, lw1, lb1, lw2, lb2, lw3, lb3,
                                       lw4, lb4, lw5, lb5, out);
}